// Round 6
// baseline (11.071 us; speedup 1.0000x reference)
//
#include <hip/hip_runtime.h>
#include <math.h>

#define TPB     256
#define WARM    48    // contraction K<=0.731: truncation far below fp32 noise (verified R3-R5)
#define ML_C    2.9086f
#define SL_C    1.898f
#define SPIN_C  365
#define TRAIN_C 4000
#define NY      15    // ceil((TRAIN_C - SPIN_C) / TPB)
#define LOG2E_F 1.4426950408889634f
#define LN2_F   0.6931471805599453f

#if __has_builtin(__builtin_amdgcn_exp2f)
#define EXP2F(x) __builtin_amdgcn_exp2f(x)
#else
#define EXP2F(x) exp2f(x)
#endif

__global__ __launch_bounds__(TPB)
void mcpbrnn_kernel(const float2* __restrict__ x2,
                    const float*  __restrict__ y_obs, int ylen,
                    const float*  __restrict__ w_om,
                    const float*  __restrict__ w_gw,
                    const float*  __restrict__ w_lm,
                    const float*  __restrict__ w_fm,
                    const float*  __restrict__ b0p,
                    const float*  __restrict__ wb2p,
                    const int*    __restrict__ tlagp,
                    float* __restrict__ out, int B)
{
    __shared__ float4 s_w[WARM + TPB];   // (u1, u2*log2e, ol*log2e, K-ol-1)
    __shared__ float  s_r[2 * (TPB / 64)];

    const int tid = threadIdx.x;
    const int B0  = blockIdx.x * TPB;
    const int b   = B0 + tid;

    // ---- issue ALL independent global loads up front (no predicates on
    //      addresses -> nothing serializes behind the tl scalar load) ----
    float yv[NY];
    #pragma unroll
    for (int k = 0; k < NY; ++k) {
        const int i = SPIN_C + tid + k * TPB;
        yv[k] = (i < TRAIN_C) ? y_obs[i] : 0.0f;   // predicate is compile-time-ish (tid only)
    }
    const float2 xown = x2[b];                      // this lane's own step input
    const int g0  = B0 - WARM + tid;
    const int gc0 = min(max(g0, 0), B - 1);
    const float2 xs0 = x2[gc0];                     // staging load, clamped index
    float2 xs1 = make_float2(0.0f, 0.0f);
    const int g1 = g0 + TPB;
    if (tid < WARM) xs1 = x2[min(g1, B - 1)];       // tail of the window

    const int tl = tlagp[0];

    // ---- gate constants (scalar broadcast loads, ref association order) ----
    const float e_om = expf(w_om[0]);
    const float e_gw = expf(w_gw[0]);
    const float e_lm = expf(w_lm[0]);
    const float e_fm = expf(w_fm[0]);
    const float denom = e_om + e_lm + e_fm + e_gw;
    const float oo   = e_om / denom;
    const float oogw = e_gw / denom;
    const float ol1  = e_lm / denom;
    const float b0   = b0p[0];
    const float wb2  = wb2p[0];
    const float K    = (1.0f - oo) - oogw;          // f = relu(K - olc_raw)
    // sigmoid argument pre-scaled by log2e:  z*log2e = fma(u2, cs1, cs0)
    const float cs1 = wb2 * (LOG2E_F / SL_C);
    const float cs0 = fmaf(-ML_C, cs1, b0 * LOG2E_F);

    // ---- own-lane ol (epilogue fidelity path, matches R3-R5 numerics) ----
    const float u2o = xown.y;
    const float olo = ol1 / (1.0f + __expf(-(b0 + (u2o - ML_C) / SL_C * wb2)));
    const bool  m   = (b >= tl);
    const float z0  = 0.0f;

    // ---- cb-independent stores: issue now, hide under everything else ----
    out[5 * B + b]  = z0;                 // bp_n
    out[6 * B + b]  = z0;                 // Gate_ib
    out[7 * B + b]  = m ? oo   : z0;      // g_oo
    out[8 * B + b]  = m ? oogw : z0;      // g_oogw
    out[9 * B + b]  = m ? olo  : z0;      // g_ol

    // ---- stage window [B0-WARM, B0+TPB); zero (u1,u2) where g<tl or OOB.
    //      Zeroed inputs provably keep c==0 => time_lag gating is free. ----
    {
        const bool live0 = (g0 >= tl) && (g0 < B);
        const float u1 = live0 ? xs0.x : 0.0f;
        const float u2 = live0 ? xs0.y : 0.0f;
        const float e2 = EXP2F(-fmaf(u2, cs1, cs0));
        const float ol = ol1 * __builtin_amdgcn_rcpf(1.0f + e2);
        s_w[tid] = make_float4(u1, u2 * LOG2E_F, ol * LOG2E_F, (K - ol) - 1.0f);
    }
    if (tid < WARM) {
        const bool live1 = (g1 >= tl) && (g1 < B);
        const float u1 = live1 ? xs1.x : 0.0f;
        const float u2 = live1 ? xs1.y : 0.0f;
        const float e2 = EXP2F(-fmaf(u2, cs1, cs0));
        const float ol = ol1 * __builtin_amdgcn_rcpf(1.0f + e2);
        s_w[tid + TPB] = make_float4(u1, u2 * LOG2E_F, ol * LOG2E_F, (K - ol) - 1.0f);
    }

    // ---- obs_std wave butterfly BEFORE the barrier (loads landed already);
    //      partials go through the same single barrier as the staging ----
    float ps = 0.0f, ps2 = 0.0f;
    #pragma unroll
    for (int k = 0; k < NY; ++k) { ps += yv[k]; ps2 = fmaf(yv[k], yv[k], ps2); }
    #pragma unroll
    for (int off = 32; off > 0; off >>= 1) {
        ps  += __shfl_xor(ps,  off);
        ps2 += __shfl_xor(ps2, off);
    }
    if ((tid & 63) == 0) {
        const int wid = tid >> 6;
        s_r[2 * wid] = ps; s_r[2 * wid + 1] = ps2;
    }
    __syncthreads();   // the ONLY barrier

    // ---- 48-step warmup chain (path: rcp->fma->exp2->add->sel->sel->max->fma) ----
    float c = 0.0f;
    #pragma unroll 8
    for (int s = 0; s < WARM; ++s) {
        const float4 v = s_w[tid + s];
        const float y0 = __builtin_amdgcn_rcpf(c);     // 1/c (1-2 ulp)
        const float aL = fmaf(-v.y, y0, v.z);          // (ol - u2/c)*log2e
        const float e  = EXP2F(aL);                    // exp(ol - u2/c)
        const float t0 = v.w + 1.0f;                   // K - ol       (c<=0; >0 always)
        const float t1 = fmaf(aL, LN2_F, t0);          // K - u2/c     (a>0)
        const float t2 = v.w + e;                      // K-ol-1+e^a   (a<=0)
        float f = (aL > 0.0f) ? t1 : t2;
        f = (c > 0.0f) ? f : t0;                       // NaN-safe: last select
        f = fmaxf(f, 0.0f);
        c = fmaf(f, c, v.x);
    }
    const float cb = c;   // state entering step b == c_n diagnostic

    // ---- finish obs_std: 8 LDS floats, no extra barrier ----
    float ts = 0.0f, ts2 = 0.0f;
    #pragma unroll
    for (int w = 0; w < TPB / 64; ++w) { ts += s_r[2 * w]; ts2 += s_r[2 * w + 1]; }
    const float nn = (float)(TRAIN_C - SPIN_C);
    const float obsstd = sqrtf((ts2 - ts * ts / nn) / (nn - 1.0f));

    // ---- remaining outputs at step b (IEEE div + expm1f for fidelity) ----
    const bool  pos  = cb > 0.0f;
    const float safe = pos ? cb : 1.0f;
    const float t    = u2o / safe;
    const float a    = olo - t;
    const float eluv = (a > 0.0f) ? a : expm1f(a);
    const float olc_raw = pos ? (olo - eluv) : olo;
    const float f   = fmaxf(K - olc_raw, 0.0f);
    const float olc = fmaxf(olc_raw, 0.0f);

    const float h = m ? oo * cb : z0;
    out[b]          = h;                          // h_n
    out[B + b]      = m ? cb : z0;                // c_n
    out[2 * B + b]  = m ? olo * cb : z0;          // l_n
    out[3 * B + b]  = m ? olc * cb : z0;          // lc_n
    out[4 * B + b]  = m ? oogw * cb : z0;         // gw_n
    out[10 * B + b] = m ? olc : z0;               // g_olc
    out[11 * B + b] = m ? f : z0;                 // g_f
    ((float2*)(out + 12 * B))[b] = make_float2(h, m ? obsstd : z0);  // h_nout (B,2)
    out[14 * B + b] = m ? obsstd : z0;            // obs_std (B,1)
}

extern "C" void kernel_launch(void* const* d_in, const int* in_sizes, int n_in,
                              void* d_out, int out_size, void* d_ws, size_t ws_size,
                              hipStream_t stream) {
    const float2* x2  = (const float2*)d_in[0];
    const float* yobs = (const float*)d_in[1];
    const float* wom  = (const float*)d_in[2];
    const float* wgw  = (const float*)d_in[3];
    const float* wlm  = (const float*)d_in[4];
    const float* wfm  = (const float*)d_in[5];
    const float* b0   = (const float*)d_in[6];
    const float* wb2  = (const float*)d_in[7];
    const int*   tlag = (const int*)d_in[9];     // d_in[8] = epoch (unused)

    const int B = in_sizes[0] / 2;               // x is (B, 1, 2)
    const int ylen = in_sizes[1];
    const int grid = (B + TPB - 1) / TPB;

    hipLaunchKernelGGL(mcpbrnn_kernel, dim3(grid), dim3(TPB), 0, stream,
                       x2, yobs, ylen, wom, wgw, wlm, wfm, b0, wb2, tlag,
                       (float*)d_out, B);
}